// Round 1
// baseline (169.202 us; speedup 1.0000x reference)
//
#include <hip/hip_runtime.h>

#define TOPK 13
#define FEPS 1e-9f
#define MAXNA 8400

__device__ __forceinline__ float pow6(float x){ float x2 = x*x; return x2*x2*x2; }

// IoU of two axis-aligned boxes given (x1,y1,x2,y2) and precomputed gt area.
__device__ __forceinline__ float iou_box(float4 g, float ag, float4 p){
    float iw = fminf(g.z, p.z) - fmaxf(g.x, p.x); iw = fmaxf(iw, 0.0f);
    float ih = fminf(g.w, p.w) - fmaxf(g.y, p.y); ih = fmaxf(ih, 0.0f);
    float inter = iw * ih;
    float ap = (p.z - p.x) * (p.w - p.y);
    float uni = ag + ap - inter + FEPS;
    return inter / uni;
}

// K0: precompute axis-aligned boxes for pd polys and gt polys (+ gt area).
__global__ void k_prep(const float* __restrict__ pd_bboxes, const float* __restrict__ gt_bboxes,
                       float* __restrict__ pd_box, float* __restrict__ gtb, float* __restrict__ gt_area,
                       int bs, int na, int ngt){
    int i = blockIdx.x * blockDim.x + threadIdx.x;
    if (i < bs * na){
        const float* p = pd_bboxes + (size_t)i * 9;
        float xmin = fminf(fminf(p[0], p[2]), fminf(p[4], p[6]));
        float xmax = fmaxf(fmaxf(p[0], p[2]), fmaxf(p[4], p[6]));
        float ymin = fminf(fminf(p[1], p[3]), fminf(p[5], p[7]));
        float ymax = fmaxf(fmaxf(p[1], p[3]), fmaxf(p[5], p[7]));
        ((float4*)pd_box)[i] = make_float4(xmin, ymin, xmax, ymax);
    }
    if (i < bs * ngt){
        const float* g = gt_bboxes + (size_t)i * 9;
        float xmin = fminf(fminf(g[0], g[2]), fminf(g[4], g[6]));
        float xmax = fmaxf(fmaxf(g[0], g[2]), fmaxf(g[4], g[6]));
        float ymin = fminf(fminf(g[1], g[3]), fminf(g[5], g[7]));
        float ymax = fmaxf(fmaxf(g[1], g[3]), fmaxf(g[5], g[7]));
        ((float4*)gtb)[i] = make_float4(xmin, ymin, xmax, ymax);
        gt_area[i] = (xmax - xmin) * (ymax - ymin);
    }
}

// K1: one block per (b,gt) row. Fill metric row in LDS, extract top-13 with
// jax.lax.top_k tie semantics (lowest index wins on ties), filter by in_gts.
__global__ __launch_bounds__(256) void k_topk(
    const float* __restrict__ pd_scores, const float* __restrict__ anc,
    const int* __restrict__ gt_labels, const float* __restrict__ gt_bboxes,
    const float* __restrict__ mask_gt, const float* __restrict__ pd_box,
    const float* __restrict__ gtb, const float* __restrict__ gt_area,
    int* __restrict__ sel, int na, int nc, int ngt)
{
    __shared__ float sm[MAXNA];
    __shared__ unsigned char sf[MAXNA];
    __shared__ float rv[256];
    __shared__ int   ri[256];
    int row = blockIdx.x;              // b*ngt + gt
    int b   = row / ngt;
    int tid = threadIdx.x;

    if (mask_gt[row] == 0.0f){
        if (tid < TOPK) sel[row * TOPK + tid] = -1;
        return;
    }

    const float* g = gt_bboxes + (size_t)row * 9;
    float ltx = g[0], lty = g[1];
    float lbx = g[2], lby = g[3];
    float rbx = g[4], rby = g[5];
    float rtx = g[6], rty = g[7];
    float vwx = rtx - ltx, vwy = rty - lty;
    float vhx = lbx - ltx, vhy = lby - lty;
    float4 gb = ((const float4*)gtb)[row];
    float  ag = gt_area[row];
    int lab = gt_labels[row];
    const float* sc = pd_scores + ((size_t)b * na) * nc + lab;
    const float4* pb = (const float4*)pd_box + (size_t)b * na;

    for (int a = tid; a < na; a += 256){
        float ax = anc[2*a], ay = anc[2*a+1];
        float fltx = ax - ltx, flty = ay - lty;
        float flbx = ax - lbx, flby = ay - lby;
        float frbx = ax - rbx, frby = ay - rby;
        float frtx = ax - rtx, frty = ay - rty;
        bool in =
            ( fltx*vwx + flty*vwy)  > FEPS &&
            ( fltx*vhx + flty*vhy)  > FEPS &&
            ( flbx*vwx + flby*vwy)  > FEPS &&
            (-(flbx*vhx + flby*vhy)) > FEPS &&
            (-(frbx*vwx + frby*vwy)) > FEPS &&
            (-(frbx*vhx + frby*vhy)) > FEPS &&
            (-(frtx*vwx + frty*vwy)) > FEPS &&
            ( frtx*vhx + frty*vhy)  > FEPS;
        float iou = iou_box(gb, ag, pb[a]);
        float metric = in ? sc[(size_t)a * nc] * pow6(iou) : 0.0f;
        sm[a] = metric;
        sf[a] = in ? 1 : 0;
    }
    __syncthreads();

    for (int k = 0; k < TOPK; ++k){
        float bv = -1.0f; int bi = na;
        for (int a = tid; a < na; a += 256){
            float v = sm[a];
            if (v > bv){ bv = v; bi = a; }   // ascending a -> lowest idx kept on ties
        }
        rv[tid] = bv; ri[tid] = bi;
        __syncthreads();
        for (int s = 128; s > 0; s >>= 1){
            if (tid < s){
                float ov = rv[tid + s]; int oi = ri[tid + s];
                if (ov > rv[tid] || (ov == rv[tid] && oi < ri[tid])){ rv[tid] = ov; ri[tid] = oi; }
            }
            __syncthreads();
        }
        if (tid == 0){
            int idx = ri[0];
            sel[row * TOPK + k] = sf[idx] ? idx : -1;  // mask_topk * mask_in_gts
            sm[idx] = -1.0f;                           // remove from candidates
        }
        __syncthreads();
    }
}

// K2: scatter selections -> per-anchor count + (racy-but-benign) assigned gt.
__global__ void k_count(const int* __restrict__ sel, int* __restrict__ fg_count,
                        int* __restrict__ assigned, int na, int ngt, int total){
    int i = blockIdx.x * blockDim.x + threadIdx.x;
    if (i >= total) return;
    int row = i / TOPK;
    int b = row / ngt, gt = row - b * ngt;
    int s = sel[i];
    if (s >= 0){
        atomicAdd(&fg_count[b * na + s], 1);
        assigned[b * na + s] = gt;   // unique writer iff fg==1 (only case it is read)
    }
}

// K3: per anchor — resolve multi-assignment, write labels/bboxes/fg/gt_idx,
// accumulate per-gt pos_align / pos_over via float-as-int atomicMax (vals >= 0).
__global__ void k_resolve(const float* __restrict__ pd_scores, const int* __restrict__ gt_labels,
                          const float* __restrict__ gt_bboxes, const float* __restrict__ pd_box,
                          const float* __restrict__ gtb, const float* __restrict__ gt_area,
                          const int* __restrict__ fg_count, const int* __restrict__ assigned,
                          float* __restrict__ out_labels, float* __restrict__ out_bbox,
                          float* __restrict__ out_fg, float* __restrict__ out_gtidx,
                          int* __restrict__ final_g, float* __restrict__ am_val,
                          float* __restrict__ pos_align, float* __restrict__ pos_over,
                          int bs, int na, int nc, int ngt)
{
    int i = blockIdx.x * blockDim.x + threadIdx.x;
    if (i >= bs * na) return;
    int b = i / na, a = i - b * na;
    int fg = fg_count[i];
    float4 p = ((const float4*)pd_box)[i];

    int g;
    if (fg > 1){
        // is_max: argmax over ALL gts (incl. mask_gt==0 ones), ties -> lowest g
        float best = -1.0f; int bi = 0;
        for (int gg = 0; gg < ngt; ++gg){
            float iou = iou_box(((const float4*)gtb)[b*ngt+gg], gt_area[b*ngt+gg], p);
            if (iou > best){ best = iou; bi = gg; }
        }
        g = bi;
    } else if (fg == 1){
        g = assigned[i];
    } else {
        g = 0;
    }
    bool pos = fg > 0;
    int lab = gt_labels[b * ngt + g];

    out_labels[i] = (float)lab;
    const float* gsrc = gt_bboxes + (size_t)(b * ngt + g) * 9;
    float* bdst = out_bbox + (size_t)i * 9;
    #pragma unroll
    for (int j = 0; j < 9; ++j) bdst[j] = gsrc[j];
    out_fg[i]    = pos ? 1.0f : 0.0f;
    out_gtidx[i] = (float)g;

    if (pos){
        float iou = iou_box(((const float4*)gtb)[b*ngt+g], gt_area[b*ngt+g], p);
        float am  = pd_scores[((size_t)b * na + a) * nc + lab] * pow6(iou);
        atomicMax((int*)&pos_align[b * ngt + g], __float_as_int(am));
        atomicMax((int*)&pos_over [b * ngt + g], __float_as_int(iou));
        final_g[i] = g;
        am_val[i]  = am;
    } else {
        final_g[i] = -1;
        am_val[i]  = 0.0f;
    }
}

// K4: one thread per output score element (coalesced stores).
__global__ void k_scores(const int* __restrict__ gt_labels, const int* __restrict__ final_g,
                         const float* __restrict__ am_val, const float* __restrict__ pos_align,
                         const float* __restrict__ pos_over, float* __restrict__ out_scores,
                         int na, int nc, int ngt, long long total)
{
    long long i = (long long)blockIdx.x * blockDim.x + threadIdx.x;
    if (i >= total) return;
    int c = (int)(i % nc);
    long long an = i / nc;          // b*na + a
    int b = (int)(an / na);
    int g = final_g[an];
    float v = 0.0f;
    if (g >= 0){
        int lab = gt_labels[b * ngt + g];
        if (c == lab){
            float pa = pos_align[b * ngt + g];
            float po = pos_over [b * ngt + g];
            v = am_val[an] * po / (pa + FEPS);
        }
    }
    out_scores[i] = v;
}

extern "C" void kernel_launch(void* const* d_in, const int* in_sizes, int n_in,
                              void* d_out, int out_size, void* d_ws, size_t ws_size,
                              hipStream_t stream)
{
    const float* pd_scores = (const float*)d_in[0];
    const float* pd_bboxes = (const float*)d_in[1];
    const float* anc       = (const float*)d_in[2];
    const int*   gt_labels = (const int*)  d_in[3];
    const float* gt_bboxes = (const float*)d_in[4];
    const float* mask_gt   = (const float*)d_in[5];

    int na  = in_sizes[2] / 2;
    int bs  = in_sizes[1] / (na * 9);
    int nc  = in_sizes[0] / (bs * na);
    int ngt = in_sizes[4] / (bs * 9);

    // workspace carve-out (256B aligned)
    char* w = (char*)d_ws;
    auto carve = [&](size_t bytes) -> char* {
        char* p = w; w += (bytes + 255) & ~(size_t)255; return p;
    };
    float* pd_box    = (float*)carve((size_t)bs * na * 4 * sizeof(float));
    float* gtb       = (float*)carve((size_t)bs * ngt * 4 * sizeof(float));
    float* gt_area   = (float*)carve((size_t)bs * ngt * sizeof(float));
    int*   sel       = (int*)  carve((size_t)bs * ngt * TOPK * sizeof(int));
    int*   fg_count  = (int*)  carve((size_t)bs * na * sizeof(int));
    int*   assigned  = (int*)  carve((size_t)bs * na * sizeof(int));
    int*   final_g   = (int*)  carve((size_t)bs * na * sizeof(int));
    float* am_val    = (float*)carve((size_t)bs * na * sizeof(float));
    float* pos_align = (float*)carve((size_t)bs * ngt * sizeof(float));
    float* pos_over  = (float*)carve((size_t)bs * ngt * sizeof(float));

    // output layout: labels | bboxes | scores | fg_mask | gt_idx (all as f32)
    float* out = (float*)d_out;
    size_t nAnch = (size_t)bs * na;
    float* o_labels = out;
    float* o_bbox   = o_labels + nAnch;
    float* o_scores = o_bbox   + nAnch * 9;
    float* o_fg     = o_scores + nAnch * nc;
    float* o_gtidx  = o_fg     + nAnch;

    hipMemsetAsync(fg_count,  0, (size_t)bs * na * sizeof(int), stream);
    hipMemsetAsync(pos_align, 0, (size_t)bs * ngt * sizeof(float), stream);
    hipMemsetAsync(pos_over,  0, (size_t)bs * ngt * sizeof(float), stream);

    int threads = 256;
    int nAnchBlocks = (bs * na + threads - 1) / threads;

    k_prep<<<nAnchBlocks, threads, 0, stream>>>(pd_bboxes, gt_bboxes, pd_box, gtb, gt_area, bs, na, ngt);

    k_topk<<<bs * ngt, threads, 0, stream>>>(pd_scores, anc, gt_labels, gt_bboxes, mask_gt,
                                             pd_box, gtb, gt_area, sel, na, nc, ngt);

    int totalSel = bs * ngt * TOPK;
    k_count<<<(totalSel + threads - 1) / threads, threads, 0, stream>>>(sel, fg_count, assigned, na, ngt, totalSel);

    k_resolve<<<nAnchBlocks, threads, 0, stream>>>(pd_scores, gt_labels, gt_bboxes, pd_box, gtb, gt_area,
                                                   fg_count, assigned,
                                                   o_labels, o_bbox, o_fg, o_gtidx,
                                                   final_g, am_val, pos_align, pos_over,
                                                   bs, na, nc, ngt);

    long long totalScores = (long long)bs * na * nc;
    int scoreBlocks = (int)((totalScores + threads - 1) / threads);
    k_scores<<<scoreBlocks, threads, 0, stream>>>(gt_labels, final_g, am_val, pos_align, pos_over,
                                                  o_scores, na, nc, ngt, totalScores);
}

// Round 2
// 101.155 us; speedup vs baseline: 1.6727x; 1.6727x over previous
//
#include <hip/hip_runtime.h>

#define TOPK 13
#define FEPS 1e-9f

__device__ __forceinline__ float pow6(float x){ float x2 = x*x; return x2*x2*x2; }

__device__ __forceinline__ unsigned long long shfl_xor_u64(unsigned long long v, int m){
    unsigned int lo = (unsigned int)v, hi = (unsigned int)(v >> 32);
    lo = __shfl_xor(lo, m);
    hi = __shfl_xor(hi, m);
    return ((unsigned long long)hi << 32) | lo;
}

// IoU of two axis-aligned boxes given (x1,y1,x2,y2) and precomputed gt area.
__device__ __forceinline__ float iou_box(float4 g, float ag, float4 p){
    float iw = fminf(g.z, p.z) - fmaxf(g.x, p.x); iw = fmaxf(iw, 0.0f);
    float ih = fminf(g.w, p.w) - fmaxf(g.y, p.y); ih = fmaxf(ih, 0.0f);
    float inter = iw * ih;
    float ap = (p.z - p.x) * (p.w - p.y);
    float uni = ag + ap - inter + FEPS;
    return inter / uni;
}

// K0: precompute axis-aligned boxes for pd polys and gt polys (+ gt area).
__global__ void k_prep(const float* __restrict__ pd_bboxes, const float* __restrict__ gt_bboxes,
                       float* __restrict__ pd_box, float* __restrict__ gtb, float* __restrict__ gt_area,
                       int bs, int na, int ngt){
    int i = blockIdx.x * blockDim.x + threadIdx.x;
    if (i < bs * na){
        const float* p = pd_bboxes + (size_t)i * 9;
        float xmin = fminf(fminf(p[0], p[2]), fminf(p[4], p[6]));
        float xmax = fmaxf(fmaxf(p[0], p[2]), fmaxf(p[4], p[6]));
        float ymin = fminf(fminf(p[1], p[3]), fminf(p[5], p[7]));
        float ymax = fmaxf(fmaxf(p[1], p[3]), fmaxf(p[5], p[7]));
        ((float4*)pd_box)[i] = make_float4(xmin, ymin, xmax, ymax);
    }
    if (i < bs * ngt){
        const float* g = gt_bboxes + (size_t)i * 9;
        float xmin = fminf(fminf(g[0], g[2]), fminf(g[4], g[6]));
        float xmax = fmaxf(fmaxf(g[0], g[2]), fmaxf(g[4], g[6]));
        float ymin = fminf(fminf(g[1], g[3]), fminf(g[5], g[7]));
        float ymax = fmaxf(fmaxf(g[1], g[3]), fmaxf(g[5], g[7]));
        ((float4*)gtb)[i] = make_float4(xmin, ymin, xmax, ymax);
        gt_area[i] = (xmax - xmin) * (ymax - ymin);
    }
}

// K1: one block per (b,gt) row. Per-thread register top-13 (u64 key = value
// desc, index asc — exact jax.lax.top_k tie semantics, in-gts flag in LSB),
// then 13 shuffle+4-slot-LDS merge passes. No big LDS arrays.
__global__ __launch_bounds__(256) void k_topk(
    const float* __restrict__ pd_scores, const float* __restrict__ anc,
    const int* __restrict__ gt_labels, const float* __restrict__ gt_bboxes,
    const float* __restrict__ mask_gt, const float* __restrict__ pd_box,
    const float* __restrict__ gtb, const float* __restrict__ gt_area,
    int* __restrict__ sel, int na, int nc, int ngt)
{
    __shared__ unsigned long long wmax[4];
    int row = blockIdx.x;              // b*ngt + gt
    int b   = row / ngt;
    int tid = threadIdx.x;

    if (mask_gt[row] == 0.0f){
        if (tid < TOPK) sel[row * TOPK + tid] = -1;
        return;
    }

    const float* g = gt_bboxes + (size_t)row * 9;
    float ltx = g[0], lty = g[1];
    float lbx = g[2], lby = g[3];
    float rbx = g[4], rby = g[5];
    float rtx = g[6], rty = g[7];
    float vwx = rtx - ltx, vwy = rty - lty;
    float vhx = lbx - ltx, vhy = lby - lty;
    float4 gb = ((const float4*)gtb)[row];
    float  ag = gt_area[row];
    int lab = gt_labels[row];
    const float* sc = pd_scores + ((size_t)b * na) * nc + lab;
    const float4* pb = (const float4*)pd_box + (size_t)b * na;
    const float2* an2 = (const float2*)anc;

    unsigned long long arr[TOPK];
    #pragma unroll
    for (int j = 0; j < TOPK; ++j) arr[j] = 0ull;   // sentinel < any real key

    for (int a = tid; a < na; a += 256){
        float2 ap = an2[a];
        float ax = ap.x, ay = ap.y;
        float fltx = ax - ltx, flty = ay - lty;
        float flbx = ax - lbx, flby = ay - lby;
        float frbx = ax - rbx, frby = ay - rby;
        float frtx = ax - rtx, frty = ay - rty;
        bool in =
            ( fltx*vwx + flty*vwy)  > FEPS &&
            ( fltx*vhx + flty*vhy)  > FEPS &&
            ( flbx*vwx + flby*vwy)  > FEPS &&
            (-(flbx*vhx + flby*vhy)) > FEPS &&
            (-(frbx*vwx + frby*vwy)) > FEPS &&
            (-(frbx*vhx + frby*vhy)) > FEPS &&
            (-(frtx*vwx + frty*vwy)) > FEPS &&
            ( frtx*vhx + frty*vhy)  > FEPS;
        float iou = iou_box(gb, ag, pb[a]);
        float metric = in ? sc[(size_t)a * nc] * pow6(iou) : 0.0f;
        // key: value desc (f32>=0 -> uint order), then index asc; LSB = !in
        unsigned int vb  = __float_as_uint(metric);
        unsigned int low = 0xFFFFFFFFu - (((unsigned int)a << 1) | (in ? 0u : 1u));
        unsigned long long key = ((unsigned long long)vb << 32) | low;
        if (key > arr[TOPK-1]){
            arr[TOPK-1] = key;
            #pragma unroll
            for (int j = TOPK-1; j > 0; --j){
                if (arr[j] > arr[j-1]){
                    unsigned long long t = arr[j]; arr[j] = arr[j-1]; arr[j-1] = t;
                }
            }
        }
    }

    int wid  = tid >> 6;
    int lane = tid & 63;
    for (int k = 0; k < TOPK; ++k){
        unsigned long long h = arr[0];     // per-thread list head (sorted desc)
        unsigned long long m = h;
        #pragma unroll
        for (int o = 32; o > 0; o >>= 1){
            unsigned long long other = shfl_xor_u64(m, o);
            m = other > m ? other : m;
        }
        if (lane == 0) wmax[wid] = m;
        __syncthreads();
        unsigned long long win = wmax[0];
        if (wmax[1] > win) win = wmax[1];
        if (wmax[2] > win) win = wmax[2];
        if (wmax[3] > win) win = wmax[3];
        if (h == win){                     // unique: keys are unique (idx unique)
            unsigned int packed = 0xFFFFFFFFu - (unsigned int)(win & 0xFFFFFFFFull);
            int idx = (int)(packed >> 1);
            int notin = (int)(packed & 1u);
            sel[row * TOPK + k] = notin ? -1 : idx;   // mask_topk * mask_in_gts
            #pragma unroll
            for (int j = 0; j < TOPK-1; ++j) arr[j] = arr[j+1];
            arr[TOPK-1] = 0ull;
        }
        __syncthreads();
    }
}

// K2: scatter selections -> per-anchor count + (racy-but-benign) assigned gt.
__global__ void k_count(const int* __restrict__ sel, int* __restrict__ fg_count,
                        int* __restrict__ assigned, int na, int ngt, int total){
    int i = blockIdx.x * blockDim.x + threadIdx.x;
    if (i >= total) return;
    int row = i / TOPK;
    int b = row / ngt, gt = row - b * ngt;
    int s = sel[i];
    if (s >= 0){
        atomicAdd(&fg_count[b * na + s], 1);
        assigned[b * na + s] = gt;   // unique writer iff fg==1 (only case it is read)
    }
}

// K3: per anchor — resolve multi-assignment, write labels/bboxes/fg/gt_idx,
// accumulate per-gt pos_align / pos_over via float-as-int atomicMax (vals >= 0).
__global__ void k_resolve(const float* __restrict__ pd_scores, const int* __restrict__ gt_labels,
                          const float* __restrict__ gt_bboxes, const float* __restrict__ pd_box,
                          const float* __restrict__ gtb, const float* __restrict__ gt_area,
                          const int* __restrict__ fg_count, const int* __restrict__ assigned,
                          float* __restrict__ out_labels, float* __restrict__ out_bbox,
                          float* __restrict__ out_fg, float* __restrict__ out_gtidx,
                          int* __restrict__ final_g, float* __restrict__ am_val,
                          float* __restrict__ pos_align, float* __restrict__ pos_over,
                          int bs, int na, int nc, int ngt)
{
    int i = blockIdx.x * blockDim.x + threadIdx.x;
    if (i >= bs * na) return;
    int b = i / na, a = i - b * na;
    int fg = fg_count[i];
    float4 p = ((const float4*)pd_box)[i];

    int g;
    if (fg > 1){
        // is_max: argmax over ALL gts (incl. mask_gt==0 ones), ties -> lowest g
        float best = -1.0f; int bi = 0;
        for (int gg = 0; gg < ngt; ++gg){
            float iou = iou_box(((const float4*)gtb)[b*ngt+gg], gt_area[b*ngt+gg], p);
            if (iou > best){ best = iou; bi = gg; }
        }
        g = bi;
    } else if (fg == 1){
        g = assigned[i];
    } else {
        g = 0;
    }
    bool pos = fg > 0;
    int lab = gt_labels[b * ngt + g];

    out_labels[i] = (float)lab;
    const float* gsrc = gt_bboxes + (size_t)(b * ngt + g) * 9;
    float* bdst = out_bbox + (size_t)i * 9;
    #pragma unroll
    for (int j = 0; j < 9; ++j) bdst[j] = gsrc[j];
    out_fg[i]    = pos ? 1.0f : 0.0f;
    out_gtidx[i] = (float)g;

    if (pos){
        float iou = iou_box(((const float4*)gtb)[b*ngt+g], gt_area[b*ngt+g], p);
        float am  = pd_scores[((size_t)b * na + a) * nc + lab] * pow6(iou);
        atomicMax((int*)&pos_align[b * ngt + g], __float_as_int(am));
        atomicMax((int*)&pos_over [b * ngt + g], __float_as_int(iou));
        final_g[i] = g;
        am_val[i]  = am;
    } else {
        final_g[i] = -1;
        am_val[i]  = 0.0f;
    }
}

// K4: one thread per output score element (coalesced stores).
__global__ void k_scores(const int* __restrict__ gt_labels, const int* __restrict__ final_g,
                         const float* __restrict__ am_val, const float* __restrict__ pos_align,
                         const float* __restrict__ pos_over, float* __restrict__ out_scores,
                         int na, int nc, int ngt, long long total)
{
    long long i = (long long)blockIdx.x * blockDim.x + threadIdx.x;
    if (i >= total) return;
    int c = (int)(i % nc);
    long long an = i / nc;          // b*na + a
    int b = (int)(an / na);
    int g = final_g[an];
    float v = 0.0f;
    if (g >= 0){
        int lab = gt_labels[b * ngt + g];
        if (c == lab){
            float pa = pos_align[b * ngt + g];
            float po = pos_over [b * ngt + g];
            v = am_val[an] * po / (pa + FEPS);
        }
    }
    out_scores[i] = v;
}

extern "C" void kernel_launch(void* const* d_in, const int* in_sizes, int n_in,
                              void* d_out, int out_size, void* d_ws, size_t ws_size,
                              hipStream_t stream)
{
    const float* pd_scores = (const float*)d_in[0];
    const float* pd_bboxes = (const float*)d_in[1];
    const float* anc       = (const float*)d_in[2];
    const int*   gt_labels = (const int*)  d_in[3];
    const float* gt_bboxes = (const float*)d_in[4];
    const float* mask_gt   = (const float*)d_in[5];

    int na  = in_sizes[2] / 2;
    int bs  = in_sizes[1] / (na * 9);
    int nc  = in_sizes[0] / (bs * na);
    int ngt = in_sizes[4] / (bs * 9);

    // workspace carve-out (256B aligned)
    char* w = (char*)d_ws;
    auto carve = [&](size_t bytes) -> char* {
        char* p = w; w += (bytes + 255) & ~(size_t)255; return p;
    };
    float* pd_box    = (float*)carve((size_t)bs * na * 4 * sizeof(float));
    float* gtb       = (float*)carve((size_t)bs * ngt * 4 * sizeof(float));
    float* gt_area   = (float*)carve((size_t)bs * ngt * sizeof(float));
    int*   sel       = (int*)  carve((size_t)bs * ngt * TOPK * sizeof(int));
    int*   fg_count  = (int*)  carve((size_t)bs * na * sizeof(int));
    int*   assigned  = (int*)  carve((size_t)bs * na * sizeof(int));
    int*   final_g   = (int*)  carve((size_t)bs * na * sizeof(int));
    float* am_val    = (float*)carve((size_t)bs * na * sizeof(float));
    float* pos_align = (float*)carve((size_t)bs * ngt * sizeof(float));
    float* pos_over  = (float*)carve((size_t)bs * ngt * sizeof(float));

    // output layout: labels | bboxes | scores | fg_mask | gt_idx (all as f32)
    float* out = (float*)d_out;
    size_t nAnch = (size_t)bs * na;
    float* o_labels = out;
    float* o_bbox   = o_labels + nAnch;
    float* o_scores = o_bbox   + nAnch * 9;
    float* o_fg     = o_scores + nAnch * nc;
    float* o_gtidx  = o_fg     + nAnch;

    hipMemsetAsync(fg_count,  0, (size_t)bs * na * sizeof(int), stream);
    hipMemsetAsync(pos_align, 0, (size_t)bs * ngt * sizeof(float), stream);
    hipMemsetAsync(pos_over,  0, (size_t)bs * ngt * sizeof(float), stream);

    int threads = 256;
    int nAnchBlocks = (bs * na + threads - 1) / threads;

    k_prep<<<nAnchBlocks, threads, 0, stream>>>(pd_bboxes, gt_bboxes, pd_box, gtb, gt_area, bs, na, ngt);

    k_topk<<<bs * ngt, threads, 0, stream>>>(pd_scores, anc, gt_labels, gt_bboxes, mask_gt,
                                             pd_box, gtb, gt_area, sel, na, nc, ngt);

    int totalSel = bs * ngt * TOPK;
    k_count<<<(totalSel + threads - 1) / threads, threads, 0, stream>>>(sel, fg_count, assigned, na, ngt, totalSel);

    k_resolve<<<nAnchBlocks, threads, 0, stream>>>(pd_scores, gt_labels, gt_bboxes, pd_box, gtb, gt_area,
                                                   fg_count, assigned,
                                                   o_labels, o_bbox, o_fg, o_gtidx,
                                                   final_g, am_val, pos_align, pos_over,
                                                   bs, na, nc, ngt);

    long long totalScores = (long long)bs * na * nc;
    int scoreBlocks = (int)((totalScores + threads - 1) / threads);
    k_scores<<<scoreBlocks, threads, 0, stream>>>(gt_labels, final_g, am_val, pos_align, pos_over,
                                                  o_scores, na, nc, ngt, totalScores);
}

// Round 3
// 99.462 us; speedup vs baseline: 1.7012x; 1.0170x over previous
//
#include <hip/hip_runtime.h>

#define TOPK 13
#define FEPS 1e-9f
#define CHUNK 64   // anchors per k_metric block (= one wave-width)

__device__ __forceinline__ float pow6(float x){ float x2 = x*x; return x2*x2*x2; }

__device__ __forceinline__ unsigned long long shfl_xor_u64(unsigned long long v, int m){
    unsigned int lo = (unsigned int)v, hi = (unsigned int)(v >> 32);
    lo = __shfl_xor(lo, m);
    hi = __shfl_xor(hi, m);
    return ((unsigned long long)hi << 32) | lo;
}

__device__ __forceinline__ float iou_box(float4 g, float ag, float4 p){
    float iw = fminf(g.z, p.z) - fmaxf(g.x, p.x); iw = fmaxf(iw, 0.0f);
    float ih = fminf(g.w, p.w) - fmaxf(g.y, p.y); ih = fmaxf(ih, 0.0f);
    float inter = iw * ih;
    float ap = (p.z - p.x) * (p.w - p.y);
    float uni = ag + ap - inter + FEPS;
    return inter / uni;
}

__device__ __forceinline__ void ins13(unsigned long long* arr, unsigned long long key){
    if (key > arr[TOPK-1]){
        arr[TOPK-1] = key;
        #pragma unroll
        for (int j = TOPK-1; j > 0; --j){
            if (arr[j] > arr[j-1]){
                unsigned long long t = arr[j]; arr[j] = arr[j-1]; arr[j-1] = t;
            }
        }
    }
}

// K0: axis-aligned boxes for pd/gt polys (+ gt area) + zero the accumulators.
__global__ void k_prep(const float* __restrict__ pd_bboxes, const float* __restrict__ gt_bboxes,
                       float* __restrict__ pd_box, float* __restrict__ gtb, float* __restrict__ gt_area,
                       int* __restrict__ fg_count, float* __restrict__ pos_align, float* __restrict__ pos_over,
                       int bs, int na, int ngt){
    int i = blockIdx.x * blockDim.x + threadIdx.x;
    if (i < bs * na){
        const float* p = pd_bboxes + (size_t)i * 9;
        float xmin = fminf(fminf(p[0], p[2]), fminf(p[4], p[6]));
        float xmax = fmaxf(fmaxf(p[0], p[2]), fmaxf(p[4], p[6]));
        float ymin = fminf(fminf(p[1], p[3]), fminf(p[5], p[7]));
        float ymax = fmaxf(fmaxf(p[1], p[3]), fmaxf(p[5], p[7]));
        ((float4*)pd_box)[i] = make_float4(xmin, ymin, xmax, ymax);
        fg_count[i] = 0;
    }
    if (i < bs * ngt){
        const float* g = gt_bboxes + (size_t)i * 9;
        float xmin = fminf(fminf(g[0], g[2]), fminf(g[4], g[6]));
        float xmax = fmaxf(fmaxf(g[0], g[2]), fmaxf(g[4], g[6]));
        float ymin = fminf(fminf(g[1], g[3]), fminf(g[5], g[7]));
        float ymax = fmaxf(fmaxf(g[1], g[3]), fmaxf(g[5], g[7]));
        ((float4*)gtb)[i] = make_float4(xmin, ymin, xmax, ymax);
        gt_area[i] = (xmax - xmin) * (ymax - ymin);
        pos_align[i] = 0.0f;
        pos_over[i]  = 0.0f;
    }
}

// K1: materialize align_metric rows (coalesced) + in_gts bitmask.
// block = (chunk of 64 anchors, batch b); 4 waves, each wave owns all 64
// anchors (lane==a_local) x ngt/4 gts. Scores tile staged in LDS (stride 81).
__global__ __launch_bounds__(256) void k_metric(
    const float* __restrict__ pd_scores, const float* __restrict__ anc,
    const int* __restrict__ gt_labels, const float* __restrict__ gt_bboxes,
    const float* __restrict__ mask_gt, const float* __restrict__ pd_box,
    const float* __restrict__ gtb, const float* __restrict__ gt_area,
    float* __restrict__ metric, unsigned long long* __restrict__ in_mask,
    int na, int nc, int ngt, int mask_words)
{
    __shared__ float s_sc[CHUNK * 81];
    __shared__ float s_gt[64 * 16];
    int b  = blockIdx.y;
    int a0 = blockIdx.x * CHUNK;
    int t  = threadIdx.x;

    // stage gt params (ngt <= 64)
    if (t < ngt){
        int gi = b * ngt + t;
        const float* gp = gt_bboxes + (size_t)gi * 9;
        float4 gb = ((const float4*)gtb)[gi];
        float* d = s_gt + t * 16;
        d[0]=gb.x; d[1]=gb.y; d[2]=gb.z; d[3]=gb.w;
        d[4]=gt_area[gi];
        d[5]=__int_as_float(gt_labels[gi]);
        #pragma unroll
        for (int j = 0; j < 8; ++j) d[6+j] = gp[j];
        d[14] = mask_gt[gi];
    }
    // stage score tile: CHUNK rows x nc floats (nc % 4 == 0)
    int nf4 = nc >> 2;
    for (int q = t; q < CHUNK * nf4; q += 256){
        int r = q / nf4, c4 = q - r * nf4;
        int a = a0 + r;
        float4 v = (a < na) ? ((const float4*)(pd_scores + ((size_t)b * na + a) * nc))[c4]
                            : make_float4(0,0,0,0);
        float* d = s_sc + r * 81 + c4 * 4;
        d[0]=v.x; d[1]=v.y; d[2]=v.z; d[3]=v.w;
    }
    __syncthreads();

    int a_local = t & (CHUNK-1);
    int a = a0 + a_local;
    bool valid = a < na;
    int wid = t >> 6;
    int gper = ngt >> 2;               // gts per wave
    int gbase = wid * gper;
    float2 ap = valid ? ((const float2*)anc)[a] : make_float2(-1e9f, -1e9f);
    float4 p  = valid ? ((const float4*)pd_box)[(size_t)b * na + a] : make_float4(0,0,0,0);
    float app = (p.z - p.x) * (p.w - p.y);

    for (int gi = 0; gi < gper; ++gi){
        int g = gbase + gi;
        const float* gd = s_gt + g * 16;
        if (gd[14] == 0.0f) continue;  // masked row: never read downstream
        float gx1=gd[0], gy1=gd[1], gx2=gd[2], gy2=gd[3], ag=gd[4];
        int lab = __float_as_int(gd[5]);
        float ltx=gd[6],  lty=gd[7];
        float lbx=gd[8],  lby=gd[9];
        float rbx=gd[10], rby=gd[11];
        float rtx=gd[12], rty=gd[13];
        float vwx = rtx-ltx, vwy = rty-lty;
        float vhx = lbx-ltx, vhy = lby-lty;
        float fltx = ap.x-ltx, flty = ap.y-lty;
        float flbx = ap.x-lbx, flby = ap.y-lby;
        float frbx = ap.x-rbx, frby = ap.y-rby;
        float frtx = ap.x-rtx, frty = ap.y-rty;
        bool in =
            ( fltx*vwx + flty*vwy)   > FEPS &&
            ( fltx*vhx + flty*vhy)   > FEPS &&
            ( flbx*vwx + flby*vwy)   > FEPS &&
            (-(flbx*vhx + flby*vhy)) > FEPS &&
            (-(frbx*vwx + frby*vwy)) > FEPS &&
            (-(frbx*vhx + frby*vhy)) > FEPS &&
            (-(frtx*vwx + frty*vwy)) > FEPS &&
            ( frtx*vhx + frty*vhy)   > FEPS;
        float iw = fminf(gx2, p.z) - fmaxf(gx1, p.x); iw = fmaxf(iw, 0.0f);
        float ih = fminf(gy2, p.w) - fmaxf(gy1, p.y); ih = fmaxf(ih, 0.0f);
        float inter = iw * ih;
        float iou = inter / (ag + app - inter + FEPS);
        float sc = s_sc[a_local * 81 + lab];
        float m = in ? sc * pow6(iou) : 0.0f;
        unsigned long long bal = __ballot(in && valid);
        size_t row = (size_t)b * ngt + g;
        if (valid) metric[row * na + a] = m;
        if ((t & 63) == 0) in_mask[row * mask_words + (a0 >> 6)] = bal;
    }
}

// K2: top-13 per (b,gt) row from the contiguous metric row. Register top-13
// per thread -> per-wave shfl top-13 -> single-wave merge of 52 candidates.
// fg_count/assigned atomics fused in (in-flag from bitmask, winners only).
__global__ __launch_bounds__(256) void k_topk(
    const float* __restrict__ metric, const unsigned long long* __restrict__ in_mask,
    const float* __restrict__ mask_gt,
    int* __restrict__ fg_count, int* __restrict__ assigned,
    int na, int ngt, int mask_words)
{
    __shared__ unsigned long long s_wtop[4 * TOPK];
    int row = blockIdx.x;
    int t = threadIdx.x;
    if (mask_gt[row] == 0.0f) return;
    int b = row / ngt, gt = row - b * ngt;

    const float* mrow = metric + (size_t)row * na;
    const float4* r4 = (const float4*)mrow;
    int n4 = na >> 2;

    unsigned long long arr[TOPK];
    #pragma unroll
    for (int j = 0; j < TOPK; ++j) arr[j] = 0ull;

    for (int q = t; q < n4; q += 256){
        float4 v = r4[q];
        unsigned base = (unsigned)q * 4u;
        ins13(arr, ((unsigned long long)__float_as_uint(v.x) << 32) | (0xFFFFFFFFu - base));
        ins13(arr, ((unsigned long long)__float_as_uint(v.y) << 32) | (0xFFFFFFFFu - (base+1u)));
        ins13(arr, ((unsigned long long)__float_as_uint(v.z) << 32) | (0xFFFFFFFFu - (base+2u)));
        ins13(arr, ((unsigned long long)__float_as_uint(v.w) << 32) | (0xFFFFFFFFu - (base+3u)));
    }
    for (int a2 = (n4 << 2) + t; a2 < na; a2 += 256)   // tail if na%4 != 0
        ins13(arr, ((unsigned long long)__float_as_uint(mrow[a2]) << 32) | (0xFFFFFFFFu - (unsigned)a2));

    int lane = t & 63, wid = t >> 6;
    // stage A: per-wave top-13 (no barriers)
    for (int k = 0; k < TOPK; ++k){
        unsigned long long m = arr[0];
        #pragma unroll
        for (int o = 32; o > 0; o >>= 1){
            unsigned long long other = shfl_xor_u64(m, o);
            m = other > m ? other : m;
        }
        if (arr[0] == m){              // unique holder (index embedded in key)
            #pragma unroll
            for (int j = 0; j < TOPK-1; ++j) arr[j] = arr[j+1];
            arr[TOPK-1] = 0ull;
        }
        if (lane == 0) s_wtop[wid * TOPK + k] = m;
    }
    __syncthreads();

    // stage B: wave 0 merges 4*13 = 52 candidates
    if (t < 64){
        unsigned long long cand = (lane < 4 * TOPK) ? s_wtop[lane] : 0ull;
        unsigned long long w = 0ull;
        for (int k = 0; k < TOPK; ++k){
            unsigned long long m = cand;
            #pragma unroll
            for (int o = 32; o > 0; o >>= 1){
                unsigned long long other = shfl_xor_u64(m, o);
                m = other > m ? other : m;
            }
            if (cand == m) cand = 0ull;
            if (lane == k) w = m;      // lane k keeps the k-th winner
        }
        if (lane < TOPK){
            unsigned idx = 0xFFFFFFFFu - (unsigned)(w & 0xFFFFFFFFull);
            unsigned long long word = in_mask[(size_t)row * mask_words + (idx >> 6)];
            if ((word >> (idx & 63u)) & 1ull){
                atomicAdd(&fg_count[b * na + (int)idx], 1);
                assigned[b * na + (int)idx] = gt;   // unique writer iff fg==1
            }
        }
    }
}

// K3: per anchor — resolve multi-assignment, write labels/bboxes/fg/gt_idx,
// accumulate per-gt pos_align / pos_over via float-as-int atomicMax (vals >= 0).
__global__ void k_resolve(const float* __restrict__ pd_scores, const int* __restrict__ gt_labels,
                          const float* __restrict__ gt_bboxes, const float* __restrict__ pd_box,
                          const float* __restrict__ gtb, const float* __restrict__ gt_area,
                          const int* __restrict__ fg_count, const int* __restrict__ assigned,
                          float* __restrict__ out_labels, float* __restrict__ out_bbox,
                          float* __restrict__ out_fg, float* __restrict__ out_gtidx,
                          int* __restrict__ final_g, float* __restrict__ am_val,
                          float* __restrict__ pos_align, float* __restrict__ pos_over,
                          int bs, int na, int nc, int ngt)
{
    int i = blockIdx.x * blockDim.x + threadIdx.x;
    if (i >= bs * na) return;
    int b = i / na, a = i - b * na;
    int fg = fg_count[i];
    float4 p = ((const float4*)pd_box)[i];

    int g;
    if (fg > 1){
        float best = -1.0f; int bi = 0;
        for (int gg = 0; gg < ngt; ++gg){
            float iou = iou_box(((const float4*)gtb)[b*ngt+gg], gt_area[b*ngt+gg], p);
            if (iou > best){ best = iou; bi = gg; }
        }
        g = bi;
    } else if (fg == 1){
        g = assigned[i];
    } else {
        g = 0;
    }
    bool pos = fg > 0;
    int lab = gt_labels[b * ngt + g];

    out_labels[i] = (float)lab;
    const float* gsrc = gt_bboxes + (size_t)(b * ngt + g) * 9;
    float* bdst = out_bbox + (size_t)i * 9;
    #pragma unroll
    for (int j = 0; j < 9; ++j) bdst[j] = gsrc[j];
    out_fg[i]    = pos ? 1.0f : 0.0f;
    out_gtidx[i] = (float)g;

    if (pos){
        float iou = iou_box(((const float4*)gtb)[b*ngt+g], gt_area[b*ngt+g], p);
        float am  = pd_scores[((size_t)b * na + a) * nc + lab] * pow6(iou);
        atomicMax((int*)&pos_align[b * ngt + g], __float_as_int(am));
        atomicMax((int*)&pos_over [b * ngt + g], __float_as_int(iou));
        final_g[i] = g;
        am_val[i]  = am;
    } else {
        final_g[i] = -1;
        am_val[i]  = 0.0f;
    }
}

// K4: float4 per thread, 2D grid (no 64-bit div/mod).
__global__ void k_scores(const int* __restrict__ gt_labels, const int* __restrict__ final_g,
                         const float* __restrict__ am_val, const float* __restrict__ pos_align,
                         const float* __restrict__ pos_over, float* __restrict__ out_scores,
                         int na, int nc, int ngt)
{
    int b = blockIdx.y;
    int nc4 = nc >> 2;
    unsigned j = blockIdx.x * 256u + threadIdx.x;
    if (j >= (unsigned)(na * nc4)) return;
    unsigned an = j / (unsigned)nc4;
    int c0 = (int)(j - an * (unsigned)nc4) * 4;
    float4 v = make_float4(0,0,0,0);
    int g = final_g[(size_t)b * na + an];
    if (g >= 0){
        int lab = gt_labels[b * ngt + g];
        int k = lab - c0;
        if (k >= 0 && k < 4){
            float pa = pos_align[b * ngt + g];
            float po = pos_over [b * ngt + g];
            float val = am_val[(size_t)b * na + an] * po / (pa + FEPS);
            if (k == 0) v.x = val; else if (k == 1) v.y = val;
            else if (k == 2) v.z = val; else v.w = val;
        }
    }
    ((float4*)(out_scores + (size_t)b * na * nc))[j] = v;
}

extern "C" void kernel_launch(void* const* d_in, const int* in_sizes, int n_in,
                              void* d_out, int out_size, void* d_ws, size_t ws_size,
                              hipStream_t stream)
{
    const float* pd_scores = (const float*)d_in[0];
    const float* pd_bboxes = (const float*)d_in[1];
    const float* anc       = (const float*)d_in[2];
    const int*   gt_labels = (const int*)  d_in[3];
    const float* gt_bboxes = (const float*)d_in[4];
    const float* mask_gt   = (const float*)d_in[5];

    int na  = in_sizes[2] / 2;
    int bs  = in_sizes[1] / (na * 9);
    int nc  = in_sizes[0] / (bs * na);
    int ngt = in_sizes[4] / (bs * 9);
    int mask_words = (na + 63) >> 6;

    // workspace carve-out (256B aligned)
    char* w = (char*)d_ws;
    auto carve = [&](size_t bytes) -> char* {
        char* p = w; w += (bytes + 255) & ~(size_t)255; return p;
    };
    float* pd_box    = (float*)carve((size_t)bs * na * 4 * sizeof(float));
    float* gtb       = (float*)carve((size_t)bs * ngt * 4 * sizeof(float));
    float* gt_area   = (float*)carve((size_t)bs * ngt * sizeof(float));
    int*   fg_count  = (int*)  carve((size_t)bs * na * sizeof(int));
    int*   assigned  = (int*)  carve((size_t)bs * na * sizeof(int));
    int*   final_g   = (int*)  carve((size_t)bs * na * sizeof(int));
    float* am_val    = (float*)carve((size_t)bs * na * sizeof(float));
    float* pos_align = (float*)carve((size_t)bs * ngt * sizeof(float));
    float* pos_over  = (float*)carve((size_t)bs * ngt * sizeof(float));
    unsigned long long* in_mask = (unsigned long long*)carve((size_t)bs * ngt * mask_words * sizeof(unsigned long long));
    float* metric    = (float*)carve((size_t)bs * ngt * na * sizeof(float));

    // output layout: labels | bboxes | scores | fg_mask | gt_idx (all as f32)
    float* out = (float*)d_out;
    size_t nAnch = (size_t)bs * na;
    float* o_labels = out;
    float* o_bbox   = o_labels + nAnch;
    float* o_scores = o_bbox   + nAnch * 9;
    float* o_fg     = o_scores + nAnch * nc;
    float* o_gtidx  = o_fg     + nAnch;

    int threads = 256;
    int nAnchBlocks = (bs * na + threads - 1) / threads;

    k_prep<<<nAnchBlocks, threads, 0, stream>>>(pd_bboxes, gt_bboxes, pd_box, gtb, gt_area,
                                                fg_count, pos_align, pos_over, bs, na, ngt);

    dim3 mgrid((na + CHUNK - 1) / CHUNK, bs);
    k_metric<<<mgrid, threads, 0, stream>>>(pd_scores, anc, gt_labels, gt_bboxes, mask_gt,
                                            pd_box, gtb, gt_area, metric, in_mask,
                                            na, nc, ngt, mask_words);

    k_topk<<<bs * ngt, threads, 0, stream>>>(metric, in_mask, mask_gt, fg_count, assigned,
                                             na, ngt, mask_words);

    k_resolve<<<nAnchBlocks, threads, 0, stream>>>(pd_scores, gt_labels, gt_bboxes, pd_box, gtb, gt_area,
                                                   fg_count, assigned,
                                                   o_labels, o_bbox, o_fg, o_gtidx,
                                                   final_g, am_val, pos_align, pos_over,
                                                   bs, na, nc, ngt);

    int nc4 = nc >> 2;
    dim3 sgrid((na * nc4 + threads - 1) / threads, bs);
    k_scores<<<sgrid, threads, 0, stream>>>(gt_labels, final_g, am_val, pos_align, pos_over,
                                            o_scores, na, nc, ngt);
}